// Round 2
// baseline (432.425 us; speedup 1.0000x reference)
//
#include <hip/hip_runtime.h>

#define HW_ 4096
#define KSEL 409           // int(0.1 * 4096)
#define LDSW 4128          // max(4*1032, 2*2056+pad) words

// Parallel block suffix-scan over an LDS histogram (NCOPIES privatized copies,
// padded STRIDE). Finds bin b = largest bin with count(>b) < kneed <= count(>=b).
// Writes sb[0]=bin, sb[1]=kneed-count(>b), sb[2]=count(==b). Ends with barrier.
template<int NBINS, int NCOPIES, int STRIDE>
__device__ __forceinline__ void radix_scan(const unsigned* lds, volatile unsigned* sb,
                                           unsigned kneed, int t) {
  constexpr int C = NBINS / 256;          // bins per thread (4 or 8)
  unsigned hsum[C];
  #pragma unroll
  for (int j = 0; j < C; ++j) hsum[j] = 0;
  #pragma unroll
  for (int c = 0; c < NCOPIES; ++c) {
    #pragma unroll
    for (int q = 0; q < C / 4; ++q) {
      uint4 u = *(const uint4*)&lds[c * STRIDE + C * t + 4 * q];   // ds_read_b128
      hsum[4*q+0] += u.x; hsum[4*q+1] += u.y; hsum[4*q+2] += u.z; hsum[4*q+3] += u.w;
    }
  }
  unsigned val = 0;
  #pragma unroll
  for (int j = 0; j < C; ++j) val += hsum[j];
  const int lane = t & 63, w = t >> 6;
  // wave-level inclusive suffix scan (higher t = higher bins)
  unsigned inc = val;
  #pragma unroll
  for (int off = 1; off < 64; off <<= 1) {
    unsigned u = __shfl_down(inc, off);
    if (lane + off < 64) inc += u;
  }
  if (lane == 0) sb[4 + w] = inc;         // wave total
  __syncthreads();
  unsigned above_waves = 0;
  #pragma unroll
  for (int w2 = 0; w2 < 4; ++w2) if (w2 > w) above_waves += sb[4 + w2];
  const unsigned P = inc + above_waves;   // inclusive suffix sum from this chunk
  unsigned cum = P - val;                 // count strictly above this chunk
  if (cum < kneed && kneed <= P) {        // exactly one thread: the crossing chunk
    #pragma unroll
    for (int j = C - 1; j >= 0; --j) {
      unsigned h = hsum[j];
      if (cum + h >= kneed) { sb[0] = C * t + j; sb[1] = kneed - cum; sb[2] = h; break; }
      cum += h;
    }
  }
  __syncthreads();
}

extern "C" __global__ void __launch_bounds__(256, 6)
topk_kern(const float* __restrict__ x, float* __restrict__ out) {
  __shared__ unsigned lds[LDSW];
  __shared__ unsigned sb[8];
  const int t = threadIdx.x;
  const int w = t >> 6;
  const size_t rowoff = (size_t)blockIdx.x * HW_;
  const float4* xr = (const float4*)(x + rowoff);
  float4* orow = (float4*)(out + rowoff);

  // 16 elements/thread as 4x float4 (coalesced), kept in registers.
  float4 v[4];
  #pragma unroll
  for (int j = 0; j < 4; ++j) v[j] = xr[t + j * 256];
  const float* pv = (const float*)v;      // element (j,e) = pv[4j+e], index 1024j+4t+e

  // ---------- pass 1: bits [30:21], 1024 bins, 4 per-wave copies ----------
  #pragma unroll
  for (int c = 0; c < 4; ++c)
    #pragma unroll
    for (int j = 0; j < 4; ++j) lds[c * 1032 + t + j * 256] = 0;
  __syncthreads();
  {
    unsigned* myh = &lds[w * 1032];
    #pragma unroll
    for (int i = 0; i < 16; ++i) {
      unsigned ab = __float_as_uint(pv[i]) & 0x7FFFFFFFu;
      atomicAdd(&myh[ab >> 21], 1u);
    }
  }
  __syncthreads();
  radix_scan<1024, 4, 1032>(lds, sb, KSEL, t);
  const unsigned b1 = sb[0];
  const unsigned k2 = sb[1];

  // ---------- pass 2: bits [20:10], 2048 bins, 2 copies (waves 01 / 23) ----------
  #pragma unroll
  for (int c = 0; c < 2; ++c)
    #pragma unroll
    for (int j = 0; j < 8; ++j) lds[c * 2056 + t + j * 256] = 0;
  __syncthreads();
  {
    unsigned* myh = &lds[(w >> 1) * 2056];
    #pragma unroll
    for (int i = 0; i < 16; ++i) {
      unsigned ab = __float_as_uint(pv[i]) & 0x7FFFFFFFu;
      if ((ab >> 21) == b1) atomicAdd(&myh[(ab >> 10) & 0x7FFu], 1u);
    }
  }
  __syncthreads();
  radix_scan<2048, 2, 2056>(lds, sb, k2, t);
  const unsigned b2 = sb[0];
  const unsigned k3 = sb[1];
  const unsigned P21 = (b1 << 11) | b2;   // top 21 bits of threshold

  // ---------- pass 3: bits [9:0], 1024 bins, 4 per-wave copies ----------
  #pragma unroll
  for (int c = 0; c < 4; ++c)
    #pragma unroll
    for (int j = 0; j < 4; ++j) lds[c * 1032 + t + j * 256] = 0;
  __syncthreads();
  {
    unsigned* myh = &lds[w * 1032];
    #pragma unroll
    for (int i = 0; i < 16; ++i) {
      unsigned ab = __float_as_uint(pv[i]) & 0x7FFFFFFFu;
      if ((ab >> 10) == P21) atomicAdd(&myh[ab & 0x3FFu], 1u);
    }
  }
  __syncthreads();
  radix_scan<1024, 4, 1032>(lds, sb, k3, t);
  const unsigned b3 = sb[0];
  const unsigned rem = sb[1];             // how many ==T to keep
  const unsigned ceq = sb[2];             // how many ==T exist
  const unsigned T = (P21 << 10) | b3;    // exact k-th largest |x| bit pattern

  unsigned keep = 0;
  #pragma unroll
  for (int i = 0; i < 16; ++i) {
    unsigned ab = __float_as_uint(pv[i]) & 0x7FFFFFFFu;
    if (ab > T) keep |= (1u << i);
  }

  if (rem == ceq) {
    #pragma unroll
    for (int i = 0; i < 16; ++i) {
      unsigned ab = __float_as_uint(pv[i]) & 0x7FFFFFFFu;
      if (ab == T) keep |= (1u << i);
    }
  } else {
    // Rare exact-bitwise-tie path: keep first `rem` equals in element-index
    // order. Element index = 1024j + 4t + e -> lexicographic (j, t, e).
    __syncthreads();
    unsigned* eqh = (unsigned*)lds;
    #pragma unroll
    for (int j = 0; j < 4; ++j) {
      unsigned c = 0;
      #pragma unroll
      for (int e = 0; e < 4; ++e)
        if ((__float_as_uint(pv[4*j+e]) & 0x7FFFFFFFu) == T) ++c;
      eqh[j * 256 + t] = c;
    }
    __syncthreads();
    if (t == 0) {                         // serial exclusive prefix (rare path)
      unsigned run = 0;
      for (int i = 0; i < 1024; ++i) { unsigned h = eqh[i]; eqh[i] = run; run += h; }
    }
    __syncthreads();
    #pragma unroll
    for (int j = 0; j < 4; ++j) {
      unsigned r = eqh[j * 256 + t];
      #pragma unroll
      for (int e = 0; e < 4; ++e) {
        if ((__float_as_uint(pv[4*j+e]) & 0x7FFFFFFFu) == T) {
          if (r < rem) keep |= (1u << (4*j + e));
          ++r;
        }
      }
    }
  }

  // ---------- coalesced float4 store ----------
  #pragma unroll
  for (int j = 0; j < 4; ++j) {
    float4 o;
    o.x = ((keep >> (4*j+0)) & 1u) ? v[j].x : 0.0f;
    o.y = ((keep >> (4*j+1)) & 1u) ? v[j].y : 0.0f;
    o.z = ((keep >> (4*j+2)) & 1u) ? v[j].z : 0.0f;
    o.w = ((keep >> (4*j+3)) & 1u) ? v[j].w : 0.0f;
    orow[t + j * 256] = o;
  }
}

extern "C" void kernel_launch(void* const* d_in, const int* in_sizes, int n_in,
                              void* d_out, int out_size, void* d_ws, size_t ws_size,
                              hipStream_t stream) {
  const float* x = (const float*)d_in[0];
  float* out = (float*)d_out;
  const int rows = in_sizes[0] / HW_;     // 64*256 = 16384 rows of 4096
  topk_kern<<<dim3(rows), dim3(256), 0, stream>>>(x, out);
}

// Round 3
// 427.981 us; speedup vs baseline: 1.0104x; 1.0104x over previous
//
#include <hip/hip_runtime.h>

#define HW_ 4096
#define KSEL 409               // int(0.1 * 4096)
#define T0BITS 0x3FC00000u     // bit pattern of 1.5f; filter |x| > 1.5

// Parallel block suffix-scan over a single LDS histogram.
// Finds bin b = largest bin with count(>b) < kneed <= count(>=b).
// Writes sb[0]=bin, sb[1]=kneed-count(>b), sb[2]=count(==b). Ends with barrier.
template<int NBINS>
__device__ __forceinline__ void radix_scan(const unsigned* hist, volatile unsigned* sb,
                                           unsigned kneed, int t) {
  constexpr int C = NBINS / 256;          // bins per thread (4 or 8)
  unsigned hsum[C];
  #pragma unroll
  for (int q = 0; q < C / 4; ++q) {
    uint4 u = *(const uint4*)&hist[C * t + 4 * q];   // ds_read_b128
    hsum[4*q+0] = u.x; hsum[4*q+1] = u.y; hsum[4*q+2] = u.z; hsum[4*q+3] = u.w;
  }
  unsigned val = 0;
  #pragma unroll
  for (int j = 0; j < C; ++j) val += hsum[j];
  const int lane = t & 63, w = t >> 6;
  // wave-level inclusive suffix scan (higher t = higher bins)
  unsigned inc = val;
  #pragma unroll
  for (int off = 1; off < 64; off <<= 1) {
    unsigned u = __shfl_down(inc, off);
    if (lane + off < 64) inc += u;
  }
  if (lane == 0) sb[4 + w] = inc;         // wave total
  __syncthreads();
  unsigned above_waves = 0;
  #pragma unroll
  for (int w2 = 0; w2 < 4; ++w2) if (w2 > w) above_waves += sb[4 + w2];
  const unsigned P = inc + above_waves;   // inclusive suffix sum from this chunk
  unsigned cum = P - val;                 // count strictly above this chunk
  if (cum < kneed && kneed <= P) {        // exactly one thread: the crossing chunk
    #pragma unroll
    for (int j = C - 1; j >= 0; --j) {
      unsigned h = hsum[j];
      if (cum + h >= kneed) { sb[0] = C * t + j; sb[1] = kneed - cum; sb[2] = h; break; }
      cum += h;
    }
  }
  __syncthreads();
}

extern "C" __global__ void __launch_bounds__(256, 5)
topk_kern(const float* __restrict__ x, float* __restrict__ out) {
  __shared__ unsigned h1[2048];   // pass 1: bits [30:20]
  __shared__ unsigned h2[1024];   // pass 2: bits [19:10]
  __shared__ unsigned h3[1024];   // pass 3: bits [9:0]
  __shared__ unsigned sb[8];
  const int t = threadIdx.x;
  const int lane = t & 63, w = t >> 6;
  const size_t rowoff = (size_t)blockIdx.x * HW_;
  const float4* xr = (const float4*)(x + rowoff);
  float4* orow = (float4*)(out + rowoff);

  // 16 elements/thread as 4x float4 (coalesced); abs bit patterns in VGPRs.
  float4 v[4];
  unsigned ab[16];
  #pragma unroll
  for (int j = 0; j < 4; ++j) {
    v[j] = xr[t + j * 256];
    ab[4*j+0] = __float_as_uint(v[j].x) & 0x7FFFFFFFu;
    ab[4*j+1] = __float_as_uint(v[j].y) & 0x7FFFFFFFu;
    ab[4*j+2] = __float_as_uint(v[j].z) & 0x7FFFFFFFu;
    ab[4*j+3] = __float_as_uint(v[j].w) & 0x7FFFFFFFu;
  }

  // Zero all three histograms (b128 stores) + count survivors of |x| > 1.5.
  *(uint4*)&h1[4 * t] = make_uint4(0, 0, 0, 0);
  *(uint4*)&h1[4 * t + 1024] = make_uint4(0, 0, 0, 0);
  *(uint4*)&h2[4 * t] = make_uint4(0, 0, 0, 0);
  *(uint4*)&h3[4 * t] = make_uint4(0, 0, 0, 0);
  unsigned cnt = 0;
  #pragma unroll
  for (int i = 0; i < 16; ++i) cnt += (ab[i] > T0BITS) ? 1u : 0u;
  #pragma unroll
  for (int off = 1; off < 64; off <<= 1) cnt += __shfl_down(cnt, off);
  if (lane == 0) sb[4 + w] = cnt;
  __syncthreads();
  const unsigned c0 = sb[4] + sb[5] + sb[6] + sb[7];
  const bool filt = (c0 >= KSEL);   // common case: ~547 >= 409; else exact fallback

  // ---- pass 1: bits [30:20], 2048 bins, filtered (~547 atomics not 4096) ----
  #pragma unroll
  for (int i = 0; i < 16; ++i)
    if (!filt || ab[i] > T0BITS) atomicAdd(&h1[ab[i] >> 20], 1u);
  __syncthreads();
  radix_scan<2048>(h1, sb, KSEL, t);
  const unsigned b1 = sb[0];
  const unsigned k2 = sb[1];

  // ---- pass 2: bits [19:10] among (ab>>20)==b1 (~50 atomics) ----
  #pragma unroll
  for (int i = 0; i < 16; ++i)
    if ((ab[i] >> 20) == b1) atomicAdd(&h2[(ab[i] >> 10) & 0x3FFu], 1u);
  __syncthreads();
  radix_scan<1024>(h2, sb, k2, t);
  const unsigned b2 = sb[0];
  const unsigned k3 = sb[1];
  const unsigned P21 = (b1 << 10) | b2;   // bits [30:10] of threshold

  // ---- pass 3: bits [9:0] among (ab>>10)==P21 (~few atomics) ----
  #pragma unroll
  for (int i = 0; i < 16; ++i)
    if ((ab[i] >> 10) == P21) atomicAdd(&h3[ab[i] & 0x3FFu], 1u);
  __syncthreads();
  radix_scan<1024>(h3, sb, k3, t);
  const unsigned b3 = sb[0];
  const unsigned rem = sb[1];             // how many ==T to keep
  const unsigned ceq = sb[2];             // how many ==T exist
  const unsigned T = (P21 << 10) | b3;    // exact k-th largest |x| bit pattern

  unsigned keep = 0;
  #pragma unroll
  for (int i = 0; i < 16; ++i) if (ab[i] > T) keep |= (1u << i);

  if (rem == ceq) {
    #pragma unroll
    for (int i = 0; i < 16; ++i) if (ab[i] == T) keep |= (1u << i);
  } else {
    // Rare exact-bitwise-tie path: keep first `rem` equals in element-index
    // order. Element index = 1024j + 4t + e -> lexicographic (j, t, e).
    __syncthreads();                      // h1 free for reuse after this
    unsigned* eqh = h1;
    #pragma unroll
    for (int j = 0; j < 4; ++j) {
      unsigned c = 0;
      #pragma unroll
      for (int e = 0; e < 4; ++e) if (ab[4*j+e] == T) ++c;
      eqh[j * 256 + t] = c;
    }
    __syncthreads();
    if (t == 0) {                         // serial exclusive prefix (rare path)
      unsigned run = 0;
      for (int i = 0; i < 1024; ++i) { unsigned h = eqh[i]; eqh[i] = run; run += h; }
    }
    __syncthreads();
    #pragma unroll
    for (int j = 0; j < 4; ++j) {
      unsigned r = eqh[j * 256 + t];
      #pragma unroll
      for (int e = 0; e < 4; ++e) {
        if (ab[4*j+e] == T) { if (r < rem) keep |= (1u << (4*j + e)); ++r; }
      }
    }
  }

  // ---- coalesced float4 store ----
  #pragma unroll
  for (int j = 0; j < 4; ++j) {
    float4 o;
    o.x = ((keep >> (4*j+0)) & 1u) ? v[j].x : 0.0f;
    o.y = ((keep >> (4*j+1)) & 1u) ? v[j].y : 0.0f;
    o.z = ((keep >> (4*j+2)) & 1u) ? v[j].z : 0.0f;
    o.w = ((keep >> (4*j+3)) & 1u) ? v[j].w : 0.0f;
    orow[t + j * 256] = o;
  }
}

extern "C" void kernel_launch(void* const* d_in, const int* in_sizes, int n_in,
                              void* d_out, int out_size, void* d_ws, size_t ws_size,
                              hipStream_t stream) {
  const float* x = (const float*)d_in[0];
  float* out = (float*)d_out;
  const int rows = in_sizes[0] / HW_;     // 64*256 = 16384 rows of 4096
  topk_kern<<<dim3(rows), dim3(256), 0, stream>>>(x, out);
}